// Round 1
// baseline (2982.812 us; speedup 1.0000x reference)
//
#include <hip/hip_runtime.h>
#include <hip/hip_bf16.h>

// Problem constants
#define ROWS 32768   // B*T
#define DIM  256
#define NCB  8192
#define CTILES 64    // NCB/128
#define OUT_ZQ 8388608  // ROWS*DIM

// ws layout (float offsets)
#define WS_CB    0            // codebook [8192*256]
#define WS_CNORM 2097152      // [8192]
#define WS_ENC2  2105344      // [32768]
#define WS_PVAL  2138112      // [32768*64]
#define WS_PIDX  4235264      // int[32768*64]
#define WS_PSUM  6332416      // [32768]

// ---------------- K1: codebook = cw @ proj_w.T + proj_b ----------------
__global__ __launch_bounds__(256) void k_proj(const float* __restrict__ cw,
                                              const float* __restrict__ pw,
                                              const float* __restrict__ pb,
                                              float* __restrict__ cb) {
    __shared__ float cwL[32][256];   // 32 codebook rows
    __shared__ float pwT[16][256];   // transposed proj_w chunk [k][d]
    const int t  = threadIdx.x;
    const int n0 = blockIdx.x * 32;

    // stage cw rows (contiguous 32KB block)
    {
        const float4* src = (const float4*)(cw + (size_t)n0 * 256);
        float4* dst = (float4*)(&cwL[0][0]);
        #pragma unroll
        for (int i = 0; i < 8; ++i) dst[t + 256 * i] = src[t + 256 * i];
    }

    float acc[32];
    #pragma unroll
    for (int n = 0; n < 32; ++n) acc[n] = 0.f;

    for (int kb = 0; kb < 16; ++kb) {
        __syncthreads();   // cwL ready (kb=0) / prev pwT consumed
        // thread t stages pw[t][kb*16 .. +16] into pwT[k][t]
        float4 r0 = *(const float4*)(pw + t * 256 + kb * 16 + 0);
        float4 r1 = *(const float4*)(pw + t * 256 + kb * 16 + 4);
        float4 r2 = *(const float4*)(pw + t * 256 + kb * 16 + 8);
        float4 r3 = *(const float4*)(pw + t * 256 + kb * 16 + 12);
        pwT[0][t] = r0.x;  pwT[1][t] = r0.y;  pwT[2][t] = r0.z;  pwT[3][t] = r0.w;
        pwT[4][t] = r1.x;  pwT[5][t] = r1.y;  pwT[6][t] = r1.z;  pwT[7][t] = r1.w;
        pwT[8][t] = r2.x;  pwT[9][t] = r2.y;  pwT[10][t] = r2.z; pwT[11][t] = r2.w;
        pwT[12][t] = r3.x; pwT[13][t] = r3.y; pwT[14][t] = r3.z; pwT[15][t] = r3.w;
        __syncthreads();
        #pragma unroll
        for (int k = 0; k < 16; ++k) {
            float p = pwT[k][t];
            #pragma unroll
            for (int n = 0; n < 32; ++n)
                acc[n] = fmaf(cwL[n][kb * 16 + k], p, acc[n]);
        }
    }
    float b = pb[t];
    #pragma unroll
    for (int n = 0; n < 32; ++n)
        cb[(size_t)(n0 + n) * 256 + t] = acc[n] + b;
}

// ---------------- K2: cnorm[n] = ||cb_n||^2 ; enc2[r] = ||ze_r||^2 ----------------
__global__ __launch_bounds__(256) void k_norms(const float* __restrict__ cb,
                                               const float* __restrict__ ze,
                                               float* __restrict__ cnorm,
                                               float* __restrict__ enc2) {
    const int wid  = (blockIdx.x * 256 + threadIdx.x) >> 6;  // global wave id
    const int lane = threadIdx.x & 63;
    const float* src;
    float* dstp;
    if (wid < NCB) { src = cb + (size_t)wid * 256; dstp = cnorm + wid; }
    else           { src = ze + (size_t)(wid - NCB) * 256; dstp = enc2 + (wid - NCB); }
    float4 v = ((const float4*)src)[lane];
    float s = v.x * v.x + v.y * v.y + v.z * v.z + v.w * v.w;
    #pragma unroll
    for (int m = 32; m; m >>= 1) s += __shfl_xor(s, m);
    if (lane == 0) *dstp = s;
}

// ---------------- K3: fused dist GEMM + per-(row, col-tile) argmin ----------------
__global__ __launch_bounds__(256) void k_dist(const float* __restrict__ ze,
                                              const float* __restrict__ cb,
                                              const float* __restrict__ cnorm,
                                              const float* __restrict__ enc2,
                                              float* __restrict__ pval,
                                              int*   __restrict__ pidx) {
    __shared__ float As[2][16][128];  // [k][row]
    __shared__ float Bs[2][16][128];  // [k][col]
    const int t  = threadIdx.x;
    const int tx = t & 15, ty = t >> 4;
    const int r0 = blockIdx.y * 128;
    const int c0 = blockIdx.x * 128;

    float acc[8][8];
    #pragma unroll
    for (int i = 0; i < 8; ++i)
        #pragma unroll
        for (int j = 0; j < 8; ++j) acc[i][j] = 0.f;

    const float4* A4 = (const float4*)ze;  // row stride = 64 float4
    const float4* B4 = (const float4*)cb;
    const int qr = t >> 2, qk = t & 3;     // loader mapping

    // prologue: stage kb=0
    float4 a0 = A4[(size_t)(r0 + qr) * 64 + qk];
    float4 a1 = A4[(size_t)(r0 + 64 + qr) * 64 + qk];
    float4 b0 = B4[(size_t)(c0 + qr) * 64 + qk];
    float4 b1 = B4[(size_t)(c0 + 64 + qr) * 64 + qk];
    int cur = 0;
    {
        const int kk = qk * 4;
        As[0][kk + 0][qr] = a0.x; As[0][kk + 1][qr] = a0.y; As[0][kk + 2][qr] = a0.z; As[0][kk + 3][qr] = a0.w;
        As[0][kk + 0][64 + qr] = a1.x; As[0][kk + 1][64 + qr] = a1.y; As[0][kk + 2][64 + qr] = a1.z; As[0][kk + 3][64 + qr] = a1.w;
        Bs[0][kk + 0][qr] = b0.x; Bs[0][kk + 1][qr] = b0.y; Bs[0][kk + 2][qr] = b0.z; Bs[0][kk + 3][qr] = b0.w;
        Bs[0][kk + 0][64 + qr] = b1.x; Bs[0][kk + 1][64 + qr] = b1.y; Bs[0][kk + 2][64 + qr] = b1.z; Bs[0][kk + 3][64 + qr] = b1.w;
    }
    __syncthreads();

    for (int kb = 0; kb < 16; ++kb) {
        // prefetch next k-tile into registers
        if (kb < 15) {
            const int ko = (kb + 1) * 4;
            a0 = A4[(size_t)(r0 + qr) * 64 + ko + qk];
            a1 = A4[(size_t)(r0 + 64 + qr) * 64 + ko + qk];
            b0 = B4[(size_t)(c0 + qr) * 64 + ko + qk];
            b1 = B4[(size_t)(c0 + 64 + qr) * 64 + ko + qk];
        }
        // compute current tile
        #pragma unroll
        for (int k = 0; k < 16; ++k) {
            float4 x0 = *(const float4*)&As[cur][k][ty * 8];
            float4 x1 = *(const float4*)&As[cur][k][ty * 8 + 4];
            float4 y0 = *(const float4*)&Bs[cur][k][tx * 8];
            float4 y1 = *(const float4*)&Bs[cur][k][tx * 8 + 4];
            float av[8] = {x0.x, x0.y, x0.z, x0.w, x1.x, x1.y, x1.z, x1.w};
            float bv[8] = {y0.x, y0.y, y0.z, y0.w, y1.x, y1.y, y1.z, y1.w};
            #pragma unroll
            for (int i = 0; i < 8; ++i)
                #pragma unroll
                for (int j = 0; j < 8; ++j)
                    acc[i][j] = fmaf(av[i], bv[j], acc[i][j]);
        }
        if (kb < 15) {
            const int nxt = cur ^ 1;
            const int kk = qk * 4;
            As[nxt][kk + 0][qr] = a0.x; As[nxt][kk + 1][qr] = a0.y; As[nxt][kk + 2][qr] = a0.z; As[nxt][kk + 3][qr] = a0.w;
            As[nxt][kk + 0][64 + qr] = a1.x; As[nxt][kk + 1][64 + qr] = a1.y; As[nxt][kk + 2][64 + qr] = a1.z; As[nxt][kk + 3][64 + qr] = a1.w;
            Bs[nxt][kk + 0][qr] = b0.x; Bs[nxt][kk + 1][qr] = b0.y; Bs[nxt][kk + 2][qr] = b0.z; Bs[nxt][kk + 3][qr] = b0.w;
            Bs[nxt][kk + 0][64 + qr] = b1.x; Bs[nxt][kk + 1][64 + qr] = b1.y; Bs[nxt][kk + 2][64 + qr] = b1.z; Bs[nxt][kk + 3][64 + qr] = b1.w;
            __syncthreads();
            cur = nxt;
        }
    }

    // epilogue: dist = (enc2[r] + cnorm[c]) - 2*dot ; per-row argmin over 128 cols
    float cn[8];
    #pragma unroll
    for (int j = 0; j < 8; ++j) cn[j] = cnorm[c0 + tx * 8 + j];
    #pragma unroll
    for (int i = 0; i < 8; ++i) {
        const int r = r0 + ty * 8 + i;
        const float e2 = enc2[r];
        float bvv = 1e30f;
        int   bii = 0x7fffffff;
        #pragma unroll
        for (int j = 0; j < 8; ++j) {
            float d = (e2 + cn[j]) - 2.f * acc[i][j];
            int c = c0 + tx * 8 + j;
            if (d < bvv) { bvv = d; bii = c; }
        }
        // reduce across the 16 lanes sharing this row (tx group is lane-aligned)
        #pragma unroll
        for (int m = 8; m; m >>= 1) {
            float ov = __shfl_xor(bvv, m);
            int   oi = __shfl_xor(bii, m);
            if (ov < bvv || (ov == bvv && oi < bii)) { bvv = ov; bii = oi; }
        }
        if (tx == 0) {
            pval[(size_t)r * CTILES + blockIdx.x] = bvv;
            pidx[(size_t)r * CTILES + blockIdx.x] = bii;
        }
    }
}

// ---------------- K4: combine partials, gather z_q, write outputs ----------------
__global__ __launch_bounds__(256) void k_final(const float* __restrict__ pval,
                                               const int*   __restrict__ pidx,
                                               const float* __restrict__ cb,
                                               const float* __restrict__ ze,
                                               float* __restrict__ out,
                                               float* __restrict__ psum) {
    __shared__ float bsum[4];
    const int w    = threadIdx.x >> 6;
    const int lane = threadIdx.x & 63;
    const int row  = blockIdx.x * 4 + w;

    float v  = pval[(size_t)row * CTILES + lane];
    int   id = pidx[(size_t)row * CTILES + lane];
    #pragma unroll
    for (int m = 32; m; m >>= 1) {
        float ov = __shfl_xor(v, m);
        int   oi = __shfl_xor(id, m);
        if (ov < v || (ov == v && oi < id)) { v = ov; id = oi; }
    }
    // all lanes hold the argmin now
    float4 c4 = ((const float4*)(cb + (size_t)id * 256))[lane];
    float4 e4 = ((const float4*)(ze + (size_t)row * 256))[lane];
    float4 tq, o;
    tq.x = c4.x - e4.x; tq.y = c4.y - e4.y; tq.z = c4.z - e4.z; tq.w = c4.w - e4.w;
    o.x = e4.x + tq.x;  o.y = e4.y + tq.y;  o.z = e4.z + tq.z;  o.w = e4.w + tq.w;
    ((float4*)(out + (size_t)row * 256))[lane] = o;

    float s = fabsf(tq.x) + fabsf(tq.y) + fabsf(tq.z) + fabsf(tq.w);
    #pragma unroll
    for (int m = 32; m; m >>= 1) s += __shfl_xor(s, m);
    if (lane == 0) {
        out[OUT_ZQ + 1 + row] = (float)id;   // indices section
        bsum[w] = s;
    }
    __syncthreads();
    if (threadIdx.x == 0)
        psum[blockIdx.x] = bsum[0] + bsum[1] + bsum[2] + bsum[3];
}

// ---------------- K5: finalize loss ----------------
__global__ __launch_bounds__(256) void k_loss(const float* __restrict__ psum,
                                              float* __restrict__ out) {
    __shared__ double red[256];
    double s = 0.0;
    for (int i = threadIdx.x; i < 8192; i += 256) s += (double)psum[i];
    red[threadIdx.x] = s;
    __syncthreads();
    for (int m = 128; m; m >>= 1) {
        if (threadIdx.x < m) red[threadIdx.x] += red[threadIdx.x + m];
        __syncthreads();
    }
    if (threadIdx.x == 0) {
        double mean = red[0] / (double)OUT_ZQ;
        out[OUT_ZQ] = (float)(1.25 * mean);  // lc + 0.25*lcm, identical values
    }
}

extern "C" void kernel_launch(void* const* d_in, const int* in_sizes, int n_in,
                              void* d_out, int out_size, void* d_ws, size_t ws_size,
                              hipStream_t stream) {
    const float* z_e = (const float*)d_in[0];
    const float* cw  = (const float*)d_in[1];
    const float* pw  = (const float*)d_in[2];
    const float* pb  = (const float*)d_in[3];
    float* out = (float*)d_out;
    float* ws  = (float*)d_ws;

    float* cb    = ws + WS_CB;
    float* cnorm = ws + WS_CNORM;
    float* enc2  = ws + WS_ENC2;
    float* pval  = ws + WS_PVAL;
    int*   pidx  = (int*)(ws + WS_PIDX);
    float* psum  = ws + WS_PSUM;

    k_proj<<<256, 256, 0, stream>>>(cw, pw, pb, cb);
    k_norms<<<(NCB + ROWS) / 4, 256, 0, stream>>>(cb, z_e, cnorm, enc2);
    k_dist<<<dim3(CTILES, ROWS / 128), 256, 0, stream>>>(z_e, cb, cnorm, enc2, pval, pidx);
    k_final<<<ROWS / 4, 256, 0, stream>>>(pval, pidx, cb, z_e, out, psum);
    k_loss<<<1, 256, 0, stream>>>(psum, out);
}

// Round 4
// 770.032 us; speedup vs baseline: 3.8736x; 3.8736x over previous
//
#include <hip/hip_runtime.h>
#include <hip/hip_bf16.h>

// Problem constants
#define ROWS 32768   // B*T
#define DIM  256
#define NCB  8192
#define CTILES 32    // NCB/256
#define OUT_ZQ 8388608  // ROWS*DIM

typedef _Float16 half8 __attribute__((ext_vector_type(8)));
typedef float f32x16 __attribute__((ext_vector_type(16)));

// ws layout (float offsets)
#define WS_CB    0            // codebook fp32 [8192*256]
#define WS_CNORM 2097152      // [8192]
#define WS_ENC2  2105344      // [32768]
#define WS_PSUM  2138112      // [8192]
#define WS_ZEH   2146304      // half [32768*256] panelized
#define WS_ZEL   6340608
#define WS_CBH   10534912     // half [8192*256] panelized, scaled x64
#define WS_CBL   11583488
#define WS_PVAL  12632064     // float [32768*32]
#define WS_PIDX  13680640     // ushort [32768*32]

// Panelized split layout: elem(row,k) -> (((row>>8)*32 + (k>>3))*256 + (row&255))*8 + (k&7)

// ---------------- K1: codebook = cw @ proj_w.T + proj_b ----------------
__global__ __launch_bounds__(256) void k_proj(const float* __restrict__ cw,
                                              const float* __restrict__ pw,
                                              const float* __restrict__ pb,
                                              float* __restrict__ cb) {
    __shared__ float cwL[32][256];
    __shared__ float pwT[16][256];
    const int t  = threadIdx.x;
    const int n0 = blockIdx.x * 32;
    {
        const float4* src = (const float4*)(cw + (size_t)n0 * 256);
        float4* dst = (float4*)(&cwL[0][0]);
        #pragma unroll
        for (int i = 0; i < 8; ++i) dst[t + 256 * i] = src[t + 256 * i];
    }
    float acc[32];
    #pragma unroll
    for (int n = 0; n < 32; ++n) acc[n] = 0.f;
    for (int kb = 0; kb < 16; ++kb) {
        __syncthreads();
        float4 r0 = *(const float4*)(pw + t * 256 + kb * 16 + 0);
        float4 r1 = *(const float4*)(pw + t * 256 + kb * 16 + 4);
        float4 r2 = *(const float4*)(pw + t * 256 + kb * 16 + 8);
        float4 r3 = *(const float4*)(pw + t * 256 + kb * 16 + 12);
        pwT[0][t] = r0.x;  pwT[1][t] = r0.y;  pwT[2][t] = r0.z;  pwT[3][t] = r0.w;
        pwT[4][t] = r1.x;  pwT[5][t] = r1.y;  pwT[6][t] = r1.z;  pwT[7][t] = r1.w;
        pwT[8][t] = r2.x;  pwT[9][t] = r2.y;  pwT[10][t] = r2.z; pwT[11][t] = r2.w;
        pwT[12][t] = r3.x; pwT[13][t] = r3.y; pwT[14][t] = r3.z; pwT[15][t] = r3.w;
        __syncthreads();
        #pragma unroll
        for (int k = 0; k < 16; ++k) {
            float p = pwT[k][t];
            #pragma unroll
            for (int n = 0; n < 32; ++n)
                acc[n] = fmaf(cwL[n][kb * 16 + k], p, acc[n]);
        }
    }
    float b = pb[t];
    #pragma unroll
    for (int n = 0; n < 32; ++n)
        cb[(size_t)(n0 + n) * 256 + t] = acc[n] + b;
}

// ---------------- K2: fp32 -> (hi,lo) fp16 split, panelized layout ----------------
__global__ __launch_bounds__(256) void k_split(const float* __restrict__ src,
                                               _Float16* __restrict__ hi,
                                               _Float16* __restrict__ lo,
                                               float scale) {
    const int j  = blockIdx.x * 256 + threadIdx.x;   // dest chunk id
    const int p  = j >> 13;            // panel (256 rows)
    const int kc = (j >> 8) & 31;      // k-chunk of 8
    const int r  = j & 255;            // row in panel
    const float* s4 = src + ((size_t)(p * 256 + r) * 256 + kc * 8);
    float4 v0 = *(const float4*)s4;
    float4 v1 = *(const float4*)(s4 + 4);
    float f[8] = {v0.x, v0.y, v0.z, v0.w, v1.x, v1.y, v1.z, v1.w};
    half8 h, l;
    #pragma unroll
    for (int i = 0; i < 8; ++i) {
        float x = f[i] * scale;
        _Float16 hh = (_Float16)x;
        h[i] = hh;
        l[i] = (_Float16)(x - (float)hh);
    }
    *(half8*)(hi + (size_t)j * 8) = h;
    *(half8*)(lo + (size_t)j * 8) = l;
}

// ---------------- K3: norms ----------------
__global__ __launch_bounds__(256) void k_norms(const float* __restrict__ cb,
                                               const float* __restrict__ ze,
                                               float* __restrict__ cnorm,
                                               float* __restrict__ enc2) {
    const int wid  = (blockIdx.x * 256 + threadIdx.x) >> 6;
    const int lane = threadIdx.x & 63;
    const float* src;
    float* dstp;
    if (wid < NCB) { src = cb + (size_t)wid * 256; dstp = cnorm + wid; }
    else           { src = ze + (size_t)(wid - NCB) * 256; dstp = enc2 + (wid - NCB); }
    float4 v = ((const float4*)src)[lane];
    float s = v.x * v.x + v.y * v.y + v.z * v.z + v.w * v.w;
    #pragma unroll
    for (int m = 32; m; m >>= 1) s += __shfl_xor(s, m);
    if (lane == 0) *dstp = s;
}

// ---------------- K4: MFMA dist GEMM (fp16x2, 3 passes) + per-tile argmin ----------------
__device__ __forceinline__ void gl_lds16(const void* g, void* l) {
    __builtin_amdgcn_global_load_lds(
        (const __attribute__((address_space(1))) unsigned int*)g,
        (__attribute__((address_space(3))) unsigned int*)l, 16, 0, 0);
}

__global__ __launch_bounds__(512, 2) void k_dist(
        const _Float16* __restrict__ zeh, const _Float16* __restrict__ zel,
        const _Float16* __restrict__ cbh, const _Float16* __restrict__ cbl,
        const float* __restrict__ cnorm,
        float* __restrict__ pval, unsigned short* __restrict__ pidx) {
    // [buf][arr: Ah,Al,Bh,Bl][kb][row][8] = 64 KiB
    __shared__ __align__(16) _Float16 lds[2][4][2][256][8];
    const int t    = threadIdx.x;
    const int lane = t & 63;
    const int w    = t >> 6;
    const int wm   = w >> 2, wn = w & 3;     // wave grid 2x4 -> 128x64 per wave
    const int bx   = blockIdx.x, by = blockIdx.y;
    const int g    = lane >> 5, s = lane & 31;
    const int kb   = t >> 8, rr = t & 255;   // staging decomposition (1 chunk/thread/array)

    f32x16 acc[4][2];
    #pragma unroll
    for (int m = 0; m < 4; ++m)
        #pragma unroll
        for (int n = 0; n < 2; ++n)
            #pragma unroll
            for (int r = 0; r < 16; ++r) acc[m][n][r] = 0.f;

#define STAGE(buf, ks) {                                                         \
    size_t ca = ((size_t)(by * 32 + (ks) * 2 + kb) * 256 + rr);                  \
    size_t cc = ((size_t)(bx * 32 + (ks) * 2 + kb) * 256 + rr);                  \
    gl_lds16(zeh + ca * 8, &lds[buf][0][kb][rr][0]);                             \
    gl_lds16(zel + ca * 8, &lds[buf][1][kb][rr][0]);                             \
    gl_lds16(cbh + cc * 8, &lds[buf][2][kb][rr][0]);                             \
    gl_lds16(cbl + cc * 8, &lds[buf][3][kb][rr][0]);                             \
}

    STAGE(0, 0);
    __syncthreads();

    for (int ks = 0; ks < 16; ++ks) {
        const int cur = ks & 1;
        if (ks < 15) STAGE(cur ^ 1, ks + 1);
        half8 ah[4], al[4], bh[2], bl[2];
        #pragma unroll
        for (int m = 0; m < 4; ++m) {
            ah[m] = *(const half8*)&lds[cur][0][g][wm * 128 + m * 32 + s][0];
            al[m] = *(const half8*)&lds[cur][1][g][wm * 128 + m * 32 + s][0];
        }
        #pragma unroll
        for (int n = 0; n < 2; ++n) {
            bh[n] = *(const half8*)&lds[cur][2][g][wn * 64 + n * 32 + s][0];
            bl[n] = *(const half8*)&lds[cur][3][g][wn * 64 + n * 32 + s][0];
        }
        #pragma unroll
        for (int m = 0; m < 4; ++m)
            #pragma unroll
            for (int n = 0; n < 2; ++n)
                acc[m][n] = __builtin_amdgcn_mfma_f32_32x32x16_f16(ah[m], bh[n], acc[m][n], 0, 0, 0);
        #pragma unroll
        for (int m = 0; m < 4; ++m)
            #pragma unroll
            for (int n = 0; n < 2; ++n)
                acc[m][n] = __builtin_amdgcn_mfma_f32_32x32x16_f16(ah[m], bl[n], acc[m][n], 0, 0, 0);
        #pragma unroll
        for (int m = 0; m < 4; ++m)
            #pragma unroll
            for (int n = 0; n < 2; ++n)
                acc[m][n] = __builtin_amdgcn_mfma_f32_32x32x16_f16(al[m], bh[n], acc[m][n], 0, 0, 0);
        __syncthreads();
    }
#undef STAGE

    // epilogue: val = cnorm[c] - acc/32  (= dist - enc2, rank-equivalent per row)
    float cn0 = cnorm[bx * 256 + wn * 64 + s];
    float cn1 = cnorm[bx * 256 + wn * 64 + 32 + s];
    float* sval = (float*)&lds[0][0][0][0][0];   // [256][4]
    int*   sidx = (int*)(sval + 1024);           // [256][4]

    #pragma unroll
    for (int m = 0; m < 4; ++m) {
        #pragma unroll
        for (int q = 0; q < 16; ++q) {
            float v0 = cn0 - acc[m][0][q] * 0.03125f;
            float v1 = cn1 - acc[m][1][q] * 0.03125f;
            float bv = fminf(v0, v1);
            #pragma unroll
            for (int msk = 1; msk < 32; msk <<= 1)
                bv = fminf(bv, __shfl_xor(bv, msk));
            // recover lowest index achieving bv (exact fp32 equality, bit-preserved by shfl)
            unsigned long long b0 = __ballot(v0 == bv);
            unsigned long long b1 = __ballot(v1 == bv);
            unsigned m0 = (unsigned)(b0 >> (g * 32));
            unsigned m1 = (unsigned)(b1 >> (g * 32));
            int bi = bx * 256 + wn * 64 + (m0 ? __builtin_ctz(m0) : 32 + __builtin_ctz(m1));
            if (s == 0) {
                int lr = wm * 128 + m * 32 + (q & 3) + 8 * (q >> 2) + 4 * g;
                sval[lr * 4 + wn] = bv;
                sidx[lr * 4 + wn] = bi;
            }
        }
    }
    __syncthreads();
    if (t < 256) {
        float bv = sval[t * 4]; int bi = sidx[t * 4];
        #pragma unroll
        for (int c = 1; c < 4; ++c) {
            float ov = sval[t * 4 + c]; int oi = sidx[t * 4 + c];
            if (ov < bv || (ov == bv && oi < bi)) { bv = ov; bi = oi; }
        }
        pval[(size_t)(by * 256 + t) * CTILES + bx] = bv;
        pidx[(size_t)(by * 256 + t) * CTILES + bx] = (unsigned short)bi;
    }
}

// ---------------- K5: top-2 combine, exact fp32 rescore, outputs ----------------
__global__ __launch_bounds__(256) void k_final(const float* __restrict__ pval,
                                               const unsigned short* __restrict__ pidx,
                                               const float* __restrict__ cb,
                                               const float* __restrict__ ze,
                                               const float* __restrict__ cnorm,
                                               const float* __restrict__ enc2,
                                               float* __restrict__ out,
                                               float* __restrict__ psum) {
    __shared__ float bsum[4];
    const int w    = threadIdx.x >> 6;
    const int lane = threadIdx.x & 63;
    const int row  = blockIdx.x * 4 + w;

    float v = 3.0e38f; int id = 0x7fffffff;
    if (lane < CTILES) {
        v  = pval[(size_t)row * CTILES + lane];
        id = pidx[(size_t)row * CTILES + lane];
    }
    float v1 = v; int i1 = id;
    #pragma unroll
    for (int m = 32; m; m >>= 1) {
        float ov = __shfl_xor(v1, m); int oi = __shfl_xor(i1, m);
        if (ov < v1 || (ov == v1 && oi < i1)) { v1 = ov; i1 = oi; }
    }
    float vc = (v == v1 && id == i1) ? 3.0e38f : v;
    int   ic = (v == v1 && id == i1) ? 0x7fffffff : id;
    float v2 = vc; int i2 = ic;
    #pragma unroll
    for (int m = 32; m; m >>= 1) {
        float ov = __shfl_xor(v2, m); int oi = __shfl_xor(i2, m);
        if (ov < v2 || (ov == v2 && oi < i2)) { v2 = ov; i2 = oi; }
    }

    const float4 e4 = ((const float4*)(ze + (size_t)row * 256))[lane];
    float4 c1 = ((const float4*)(cb + (size_t)i1 * 256))[lane];
    float4 c2 = ((const float4*)(cb + (size_t)i2 * 256))[lane];
    float p1 = e4.x * c1.x + e4.y * c1.y + e4.z * c1.z + e4.w * c1.w;
    float p2 = e4.x * c2.x + e4.y * c2.y + e4.z * c2.z + e4.w * c2.w;
    #pragma unroll
    for (int m = 32; m; m >>= 1) { p1 += __shfl_xor(p1, m); p2 += __shfl_xor(p2, m); }
    const float base = enc2[row];
    float d1 = (base + cnorm[i1]) - 2.0f * p1;
    float d2 = (base + cnorm[i2]) - 2.0f * p2;
    const bool two = (d2 < d1 || (d2 == d1 && i2 < i1));
    const int  win = two ? i2 : i1;
    float4 c4 = two ? c2 : c1;

    float4 tq, o;
    tq.x = c4.x - e4.x; tq.y = c4.y - e4.y; tq.z = c4.z - e4.z; tq.w = c4.w - e4.w;
    o.x = e4.x + tq.x;  o.y = e4.y + tq.y;  o.z = e4.z + tq.z;  o.w = e4.w + tq.w;
    ((float4*)(out + (size_t)row * 256))[lane] = o;

    float s = fabsf(tq.x) + fabsf(tq.y) + fabsf(tq.z) + fabsf(tq.w);
    #pragma unroll
    for (int m = 32; m; m >>= 1) s += __shfl_xor(s, m);
    if (lane == 0) {
        out[OUT_ZQ + 1 + row] = (float)win;
        bsum[w] = s;
    }
    __syncthreads();
    if (threadIdx.x == 0)
        psum[blockIdx.x] = bsum[0] + bsum[1] + bsum[2] + bsum[3];
}

// ---------------- K6: finalize loss ----------------
__global__ __launch_bounds__(256) void k_loss(const float* __restrict__ psum,
                                              float* __restrict__ out) {
    __shared__ double red[256];
    double s = 0.0;
    for (int i = threadIdx.x; i < 8192; i += 256) s += (double)psum[i];
    red[threadIdx.x] = s;
    __syncthreads();
    for (int m = 128; m; m >>= 1) {
        if (threadIdx.x < m) red[threadIdx.x] += red[threadIdx.x + m];
        __syncthreads();
    }
    if (threadIdx.x == 0) {
        double mean = red[0] / (double)OUT_ZQ;
        out[OUT_ZQ] = (float)(1.25 * mean);
    }
}

extern "C" void kernel_launch(void* const* d_in, const int* in_sizes, int n_in,
                              void* d_out, int out_size, void* d_ws, size_t ws_size,
                              hipStream_t stream) {
    const float* z_e = (const float*)d_in[0];
    const float* cw  = (const float*)d_in[1];
    const float* pw  = (const float*)d_in[2];
    const float* pb  = (const float*)d_in[3];
    float* out = (float*)d_out;
    float* ws  = (float*)d_ws;

    float*     cb    = ws + WS_CB;
    float*     cnorm = ws + WS_CNORM;
    float*     enc2  = ws + WS_ENC2;
    float*     psum  = ws + WS_PSUM;
    _Float16*  zeh   = (_Float16*)(ws + WS_ZEH);
    _Float16*  zel   = (_Float16*)(ws + WS_ZEL);
    _Float16*  cbh   = (_Float16*)(ws + WS_CBH);
    _Float16*  cbl   = (_Float16*)(ws + WS_CBL);
    float*     pval  = ws + WS_PVAL;
    unsigned short* pidx = (unsigned short*)(ws + WS_PIDX);

    k_split<<<4096, 256, 0, stream>>>(z_e, zeh, zel, 1.0f);          // 32768*32 chunks
    k_proj<<<256, 256, 0, stream>>>(cw, pw, pb, cb);
    k_split<<<1024, 256, 0, stream>>>(cb, cbh, cbl, 64.0f);          // 8192*32 chunks
    k_norms<<<(NCB + ROWS) / 4, 256, 0, stream>>>(cb, z_e, cnorm, enc2);
    k_dist<<<dim3(NCB / 256, ROWS / 256), 512, 0, stream>>>(zeh, zel, cbh, cbl, cnorm, pval, pidx);
    k_final<<<ROWS / 4, 256, 0, stream>>>(pval, pidx, cb, z_e, cnorm, enc2, out, psum);
    k_loss<<<1, 256, 0, stream>>>(psum, out);
}